// Round 13
// baseline (226.002 us; speedup 1.0000x reference)
//
#include <hip/hip_runtime.h>
#include <hip/hip_bf16.h>

#define N_NODES 100000
#define N_EDGES 1600000
#define IN_DIM 48
#define OUT_DIM 128
#define K1 144                 // 3*IN_DIM
#define NSEG (2 * N_NODES)     // 200000 segments (node x {mi,mo})
#define NMSG (2 * N_EDGES)     // 3.2M directed messages
#define NBIN 1563              // bins of 128 segments: bin = node >> 6
#define SEGPB 128              // segments per bin/block
#define BINCAP 2560            // per-bin capacity: mean 2048 + ~11 sigma
#define MAXR (BINCAP / 256)    // 10 records per thread, register-cached
#define EPB 8192               // edges per binscat block (196 blocks; r7 vs r8
                               // A/B: 84B chunks beat 42B chunks + more blocks)
#define BTHREADS 1024
#define EPT (EPB / BTHREADS)   // 8 edges per thread, register-cached
#define HPAD 132               // wave-private hsh row stride (bank-spread)

typedef unsigned short u16;
typedef unsigned long long u64;
typedef __attribute__((ext_vector_type(8))) short short8;
typedef __attribute__((ext_vector_type(4))) float f32x4;
typedef __attribute__((ext_vector_type(4))) unsigned uint4v;

// round-to-nearest-even f32 -> bf16 bits
static __device__ __forceinline__ u16 f2bf(float f) {
  unsigned u = __float_as_uint(f);
  unsigned r = (u + 0x7fffu + ((u >> 16) & 1u)) >> 16;
  return (u16)r;
}
// fast tanh: 1 - 2/(e^{2x}+1)  (v_exp_f32 + v_rcp_f32, ~1e-6 abs error)
static __device__ __forceinline__ float ftanh(float x) {
  return 1.f - 2.f * __builtin_amdgcn_rcpf(__expf(2.f * x) + 1.f);
}

// ---------------------------------------------------------------------------
// Data layouts:
//   xq[p][node][16] bf16 (p=0..2): quarter tables, 32B rows, 3.2MB each —
//     EACH FITS A 4MB PER-XCD L2. Gather runs 3 passes so the random row
//     reads of pass p hit only table p (L2-resident), vs r12's single
//     12.8MB padded table that missed ~130MB to L3/HBM.
//   W1f [nt(8)][ks(5)][lane(64)][8]  A/B-frag order, zeros for k>=144
//   W2f [nt(8)][ks(4)][lane(64)][8]
// M semantic: k<48: mi, 48..95: mo, 96..143: x, 144..159: zero.
// ---------------------------------------------------------------------------

// Stage 0a: weights -> fragment order (r7-verified)
__global__ __launch_bounds__(256) void prep_w_kernel(
    const float* __restrict__ W1, const float* __restrict__ W2,
    u16* __restrict__ W1f, u16* __restrict__ W2f)
{
  int i = blockIdx.x * 256 + threadIdx.x;
  if (i < 2560) {                       // 8 nt * 5 ks * 64 lanes
    int nt = i / 320;
    int r  = i - nt * 320;
    int ks = r >> 6, l = r & 63;
    int nrow = nt * 16 + (l & 15);
    int k0 = ks * 32 + (l >> 4) * 8;
#pragma unroll
    for (int j = 0; j < 8; ++j) {
      int k = k0 + j;
      W1f[(size_t)i * 8 + j] = (k < K1) ? f2bf(W1[nrow * K1 + k]) : (u16)0;
    }
  } else if (i < 2560 + 2048) {         // 8 nt * 4 ks * 64 lanes
    int i2 = i - 2560;
    int nt = i2 >> 8;
    int r  = i2 & 255;
    int ks = r >> 6, l = r & 63;
    int nrow = nt * 16 + (l & 15);
    int k0 = ks * 32 + (l >> 4) * 8;
#pragma unroll
    for (int j = 0; j < 8; ++j)
      W2f[(size_t)i2 * 8 + j] = f2bf(W2[nrow * OUT_DIM + k0 + j]);
  }
}

// Stage 0b: x -> three bf16 quarter tables (32B rows, no pad).
__global__ __launch_bounds__(256) void prep_x_kernel(
    const float* __restrict__ x, u16* __restrict__ xq)
{
  int i = blockIdx.x * 256 + threadIdx.x;   // over 3*N_NODES
  if (i < 3 * N_NODES) {
    int p = i / N_NODES;
    int node = i - p * N_NODES;
    const float* xr = x + (size_t)node * IN_DIM + p * 16;
    short8 v0, v1;
#pragma unroll
    for (int j = 0; j < 8; ++j) {
      v0[j] = (short)f2bf(xr[j]);
      v1[j] = (short)f2bf(xr[8 + j]);
    }
    u16* dst = xq + ((size_t)p * N_NODES + node) * 16;
    *(short8*)dst = v0;
    *(short8*)(dst + 8) = v1;
  }
}

// ---------------------------------------------------------------------------
// Phase A: binscat — partition 3.2M messages into 1563 bins (128 segs each).
// Record (8B): .x = (seg_local << 24) | src, .y = fp32 w bits.
//   dir0 (mi): dst=col -> seg even    dir1 (mo): dst=row -> seg odd
// r6-verified shape (EPB 8192, 196 blocks). Only INT LDS atomics.
// ---------------------------------------------------------------------------
__global__ __launch_bounds__(BTHREADS) void binscat_kernel(
    const int* __restrict__ eidx, const float* __restrict__ ea,
    int* __restrict__ bin_cursor, int2* __restrict__ bkt)
{
  __shared__ int hist[NBIN];   // pass1: counts; then: within-bin write cursor
  for (int i = threadIdx.x; i < NBIN; i += BTHREADS) hist[i] = 0;
  __syncthreads();

  const int e0 = blockIdx.x * EPB;
  int rows[EPT], cols[EPT], ws[EPT];

#pragma unroll
  for (int u = 0; u < EPT; ++u) {
    int e = e0 + u * BTHREADS + threadIdx.x;
    rows[u] = -1;
    if (e < N_EDGES) {
      rows[u] = eidx[e];
      cols[u] = eidx[N_EDGES + e];
      ws[u]   = __float_as_int(ea[e]);
      atomicAdd(&hist[cols[u] >> 6], 1);
      atomicAdd(&hist[rows[u] >> 6], 1);
    }
  }
  __syncthreads();

  for (int b = threadIdx.x; b < NBIN; b += BTHREADS) {
    int c = hist[b];
    hist[b] = c ? atomicAdd(&bin_cursor[b], c) : 0;
  }
  __syncthreads();

#pragma unroll
  for (int u = 0; u < EPT; ++u) {
    if (rows[u] >= 0) {
      int row = rows[u], col = cols[u], w = ws[u];
      int seg0 = col * 2;          // mi segment (even), src = row
      int seg1 = row * 2 + 1;      // mo segment (odd),  src = col
      int s0 = atomicAdd(&hist[seg0 >> 7], 1);
      if (s0 < BINCAP)
        bkt[(size_t)(seg0 >> 7) * BINCAP + s0] =
            make_int2(((seg0 & 127) << 24) | row, w);
      int s1 = atomicAdd(&hist[seg1 >> 7], 1);
      if (s1 < BINCAP)
        bkt[(size_t)(seg1 >> 7) * BINCAP + s1] =
            make_int2(((seg1 & 127) << 24) | col, w);
    }
  }
}

// ---------------------------------------------------------------------------
// binfuse v6: wave-private pipeline (r12) + 3-pass L2-resident gather.
//  1. (block-coop) sort bin's records into srec by segment (int atomics).
//  2. (wave-private) 3 passes x 4 rounds: pass p reads ONLY quarter table p
//     (3.2MB, L2-resident). 8-lane group per segment: lane=(rec_off=r8>>1,
//     c2=r8&1) -> 4 records x 32B in flight per instruction. shfl_xor(2,4)
//     merges record partitions; lanes 0-1 flush 16B each -> Msh frags.
//  3. (wave-private) MLP: layer1 from Msh(ks0-2)+xq(ks3-4) + W1f -> tanh ->
//     hsh[wave] -> layer2 + W2f -> tanh -> out.
// LDS 40,448 -> 4 blocks/CU.
// ---------------------------------------------------------------------------
__global__ __launch_bounds__(256, 4) void binfuse_kernel(
    const int2* __restrict__ bkt, const int* __restrict__ bin_cursor,
    const u16* __restrict__ xq, const u16* __restrict__ W1f,
    const float* __restrict__ b1, const u16* __restrict__ W2f,
    const float* __restrict__ b2, float* __restrict__ out)
{
  __shared__ unsigned srec[BINCAP];                  // 10,240 B sorted records
  __shared__ __align__(16) u16 Msh[4 * 3 * 64 * 8];  // 12,288 B A-frags ks0..2
  __shared__ __align__(16) u16 hsh[4][16][HPAD];     // 16,896 B wave-private h
  __shared__ int offs_sh[SEGPB];                     // hist -> inclusive scan
  __shared__ int cursor[SEGPB];

  const int b   = blockIdx.x;
  const int tid = threadIdx.x;
  const int cnt = min(bin_cursor[b], BINCAP);
  const int2* recs = bkt + (size_t)b * BINCAP;

  // ---- phase 1: reg-cache records, hist, in-place scan, scatter (coop)
  if (tid < SEGPB) offs_sh[tid] = 0;
  if (tid == SEGPB) srec[0] = 0;        // safe record if bin is empty
  __syncthreads();

  int2 rr[MAXR];
#pragma unroll
  for (int u = 0; u < MAXR; ++u) {
    int j = tid + u * 256;
    rr[u].x = -1;
    if (j < cnt) {
      rr[u] = recs[j];
      atomicAdd(&offs_sh[(unsigned)rr[u].x >> 24], 1);
    }
  }
  __syncthreads();

#pragma unroll
  for (int off = 1; off < SEGPB; off <<= 1) {
    int v = (tid < SEGPB && tid >= off) ? offs_sh[tid - off] : 0;
    __syncthreads();
    if (tid < SEGPB) offs_sh[tid] += v;
    __syncthreads();
  }
  if (tid < SEGPB) cursor[tid] = tid ? offs_sh[tid - 1] : 0;   // exclusive
  __syncthreads();

#pragma unroll
  for (int u = 0; u < MAXR; ++u) {
    if (rr[u].x >= 0) {
      int sl = (unsigned)rr[u].x >> 24;
      unsigned src = (unsigned)rr[u].x & 0xFFFFFFu;
      unsigned wb = f2bf(__int_as_float(rr[u].y));
      int slot = atomicAdd(&cursor[sl], 1);
      srec[slot] = (src << 15) | (wb & 0x7FFFu);
    }
  }
  __syncthreads();   // srec complete; from here each wave runs independently

  // ---- phase 2: wave-private gather, 3 L2-resident passes x 4 rounds
  const int wave = tid >> 6;
  const int lane = tid & 63;
  const int g    = lane >> 3;            // segment group 0..7
  const int r8   = lane & 7;
  const int rec_off = r8 >> 1;           // record slot 0..3 within group
  const int c2   = r8 & 1;               // 16B half of the 32B quarter-row

#pragma unroll
  for (int p = 0; p < 3; ++p) {
    const uint4v* xq4 = (const uint4v*)(xq + (size_t)p * N_NODES * 16);
#pragma unroll
    for (int r = 0; r < 4; ++r) {
      const int sl  = wave * 32 + r * 8 + g;
      const int beg = sl ? offs_sh[sl - 1] : 0;
      const int n   = offs_sh[sl] - beg;

      int kmax = n;
      kmax = max(kmax, __shfl_xor(kmax, 8, 64));
      kmax = max(kmax, __shfl_xor(kmax, 16, 64));
      kmax = max(kmax, __shfl_xor(kmax, 32, 64));

      float a[8];
#pragma unroll
      for (int c = 0; c < 8; ++c) a[c] = 0.f;

      for (int it = 0; it < kmax; it += 4) {
        const int jj = it + rec_off;
        const bool val = jj < n;
        unsigned rc = srec[val ? beg + jj : 0];   // LDS broadcast per pair
        float w = val ? __uint_as_float((rc & 0x7FFFu) << 16) : 0.f;
        uint4v v = xq4[(size_t)(rc >> 15) * 2 + c2];
#pragma unroll
        for (int c = 0; c < 4; ++c) {
          a[2 * c]     = fmaf(__uint_as_float(v[c] << 16),         w, a[2 * c]);
          a[2 * c + 1] = fmaf(__uint_as_float(v[c] & 0xFFFF0000u), w, a[2 * c + 1]);
        }
      }

      // merge the 4 record partitions (lanes differing in r8 bits 1-2)
#pragma unroll
      for (int c = 0; c < 8; ++c) {
        a[c] += __shfl_xor(a[c], 2, 64);
        a[c] += __shfl_xor(a[c], 4, 64);
      }

      if (r8 < 2) {                      // lane c2 writes its 8 dims (16B)
        unsigned d[4];
#pragma unroll
        for (int c = 0; c < 4; ++c)
          d[c] = (unsigned)f2bf(a[2 * c]) | ((unsigned)f2bf(a[2 * c + 1]) << 16);
        uint4v o = {d[0], d[1], d[2], d[3]};
        const int node_l = sl >> 1;      // 0..63; node_l>>4 == wave
        const int half   = sl & 1;       // 0: mi, 1: mo
        const int t      = node_l >> 4;  // == wave
        const int nl     = node_l & 15;
        const int k0     = half * 48 + p * 16 + c2 * 8;
        const int ks     = k0 >> 5;      // 0..2
        const int qq     = (k0 >> 3) & 3;
        *(uint4v*)&Msh[(((t * 3 + ks) * 64) + qq * 16 + nl) * 8] = o;
      }
    }
  }
  // NO block barrier: Msh[wave] is written and read by this wave only.

  // ---- phase 3: wave-private MLP for tile = b*4 + wave
  const int col  = lane & 15;
  const int quad = lane >> 4;
  const int nodeBase = b * 64 + wave * 16;
  if (nodeBase >= N_NODES) return;       // wave-uniform (tail bin)
  const int node16 = nodeBase + col;

  f32x4 acc[8];
#pragma unroll
  for (int nt = 0; nt < 8; ++nt) acc[nt] = (f32x4){0.f, 0.f, 0.f, 0.f};

#pragma unroll
  for (int ks = 0; ks < 5; ++ks) {
    short8 afr;
    if (ks < 3) {
      afr = *(const short8*)&Msh[(((wave * 3 + ks) * 64) + lane) * 8];
    } else if (ks == 3) {
      const int d0 = quad * 8;           // x dims 0..31 -> quarters 0,1
      afr = *(const short8*)(xq + ((size_t)(d0 >> 4) * N_NODES + node16) * 16 + (d0 & 15));
    } else {                             // ks == 4
      if (quad < 2) {
        const int d0 = 32 + quad * 8;    // x dims 32..47 -> quarter 2
        afr = *(const short8*)(xq + ((size_t)2 * N_NODES + node16) * 16 + (d0 & 15));
      } else {
        afr = (short8){0, 0, 0, 0, 0, 0, 0, 0};   // k >= 144 zero pad
      }
    }
#pragma unroll
    for (int nt = 0; nt < 8; ++nt) {
      short8 bb = *(const short8*)(W1f + ((nt * 5 + ks) * 64 + lane) * 8);
      acc[nt] = __builtin_amdgcn_mfma_f32_16x16x32_bf16(afr, bb, acc[nt], 0, 0, 0);
    }
  }

#pragma unroll
  for (int nt = 0; nt < 8; ++nt) {
    const int nn = nt * 16 + col;
    const float bb = b1[nn];
#pragma unroll
    for (int rg = 0; rg < 4; ++rg)
      hsh[wave][quad * 4 + rg][nn] = f2bf(ftanh(acc[nt][rg] + bb));
  }
  // wave-private hsh: same-wave ds_write -> ds_read, no barrier needed

  f32x4 acc2[8];
#pragma unroll
  for (int nt = 0; nt < 8; ++nt) acc2[nt] = (f32x4){0.f, 0.f, 0.f, 0.f};

#pragma unroll
  for (int ks = 0; ks < 4; ++ks) {
    short8 afr = *(const short8*)&hsh[wave][col][ks * 32 + quad * 8];
#pragma unroll
    for (int nt = 0; nt < 8; ++nt) {
      short8 bb = *(const short8*)(W2f + ((nt * 4 + ks) * 64 + lane) * 8);
      acc2[nt] = __builtin_amdgcn_mfma_f32_16x16x32_bf16(afr, bb, acc2[nt], 0, 0, 0);
    }
  }

#pragma unroll
  for (int nt = 0; nt < 8; ++nt) {
    const int nn = nt * 16 + col;
    const float bb = b2[nn];
#pragma unroll
    for (int rg = 0; rg < 4; ++rg) {
      const int node = nodeBase + quad * 4 + rg;   // < N_NODES (16|N)
      out[(size_t)node * OUT_DIM + nn] = ftanh(acc2[nt][rg] + bb);
    }
  }
}

extern "C" void kernel_launch(void* const* d_in, const int* in_sizes, int n_in,
                              void* d_out, int out_size, void* d_ws, size_t ws_size,
                              hipStream_t stream) {
  const float* x   = (const float*)d_in[0];
  const int* eidx  = (const int*)d_in[1];
  const float* ea  = (const float*)d_in[2];
  const float* W1  = (const float*)d_in[3];
  const float* b1  = (const float*)d_in[4];
  const float* W2  = (const float*)d_in[5];
  const float* b2  = (const float*)d_in[6];
  float* out = (float*)d_out;

  // workspace layout (16B-aligned), ~42 MB total:
  char* p = (char*)d_ws;
  int2* bkt       = (int2*)p;     p += (size_t)NBIN * BINCAP * 8;      // 32.0 MB
  u16* xq         = (u16*)p;      p += (size_t)3 * N_NODES * 16 * 2;   //  9.6 MB
  u16* W1f        = (u16*)p;      p += (size_t)2560 * 8 * 2;           // 40 KB
  u16* W2f        = (u16*)p;      p += (size_t)2048 * 8 * 2;           // 32 KB
  int* bin_cursor = (int*)p;      p += 2048 * 4;

  hipMemsetAsync(bin_cursor, 0, 2048 * 4, stream);

  prep_w_kernel<<<(2560 + 2048 + 255) / 256, 256, 0, stream>>>(W1, W2, W1f, W2f);
  prep_x_kernel<<<(3 * N_NODES + 255) / 256, 256, 0, stream>>>(x, xq);

  binscat_kernel<<<(N_EDGES + EPB - 1) / EPB, BTHREADS, 0, stream>>>(
      eidx, ea, bin_cursor, bkt);

  binfuse_kernel<<<NBIN, 256, 0, stream>>>(
      bkt, bin_cursor, xq, W1f, b1, W2f, b2, out);
}